// Round 5
// baseline (246.062 us; speedup 1.0000x reference)
//
#include <hip/hip_runtime.h>
#include <cstddef>

#define H 16
#define D 1024
#define DH 64
#define L 512

typedef __attribute__((ext_vector_type(8))) short bf16x8;
typedef __attribute__((ext_vector_type(4))) short bf16x4;
typedef __attribute__((ext_vector_type(4))) float f32x4;

__device__ inline short f2bf(float x) {
    union { float f; unsigned u; } c; c.f = x;
    unsigned r = (c.u + 0x7FFFu + ((c.u >> 16) & 1u)) >> 16;
    return (short)r;
}
__device__ inline float bf2f(short x) {
    union { float f; unsigned u; } c;
    c.u = ((unsigned)(unsigned short)x) << 16; return c.f;
}

__device__ inline void gload_lds16(const void* g, void* l) {
    __builtin_amdgcn_global_load_lds(
        (const __attribute__((address_space(1))) unsigned int*)g,
        (__attribute__((address_space(3))) unsigned int*)l,
        16, 0, 0);
}

// ---------------- prep: fp32->bf16 convert (5 regions) + 4 weight transposes ----------------
// blockIdx.y: 0..4 = cvt region, 5..8 = wtrans of weight y-5.
struct PrepArgs {
    const float* csrc[5]; short* cdst[5]; int cn[5];
    const float* W[4]; short* T[4];
};

__global__ __launch_bounds__(256) void prep_kernel(PrepArgs a) {
    const int y = blockIdx.y;
    if (y < 5) {
        const float* s = a.csrc[y];
        short* d = a.cdst[y];
        int n = a.cn[y];
        int i = (blockIdx.x * 256 + threadIdx.x) * 8;
        if (i >= n) return;
        float4 x0 = *(const float4*)(s + i);
        float4 x1 = *(const float4*)(s + i + 4);
        bf16x8 o;
        o[0] = f2bf(x0.x); o[1] = f2bf(x0.y); o[2] = f2bf(x0.z); o[3] = f2bf(x0.w);
        o[4] = f2bf(x1.x); o[5] = f2bf(x1.y); o[6] = f2bf(x1.z); o[7] = f2bf(x1.w);
        *(bf16x8*)(d + i) = o;
    } else {
        const float* W = a.W[y - 5];
        short* T = a.T[y - 5];
        int idx = blockIdx.x * 256 + threadIdx.x;
        if (idx >= 1024 * 128) return;
        int n = idx & 1023;
        int k0 = (idx >> 10) << 3;
        bf16x8 o;
        #pragma unroll
        for (int kk = 0; kk < 8; ++kk)
            o[kk] = f2bf(W[(size_t)(k0 + kk) * 1024 + n]);   // lanes contiguous in n
        *(bf16x8*)(T + (size_t)n * 1024 + k0) = o;
    }
}

// ---------------- MFMA GEMM, m97-style: global_load_lds + XOR-swizzled LDS ----------------
// C = (A @ Bt^T + bias) * scale.  A: (M,K) bf16 rm.  Bt: (N,K) bf16 rm.
// mode 0: fp32 flat [m][n]; mode 1: bf16 (B,H,L,DH); mode 2: bf16 (B,H,DH,L)
#define BM 128
#define BN 64
#define BKK 64

struct GemmBatch {
    const short* A[3]; const short* Bt[3]; const float* bias[3];
    void* out[3]; float scale[3]; int mode[3];
};

__global__ __launch_bounds__(256) void gemm_mfma_kernel(GemmBatch P, int M, int N, int K) {
    const int z = blockIdx.z;
    const short* __restrict__ A  = P.A[z];
    const short* __restrict__ Bt = P.Bt[z];
    const float* __restrict__ bias = P.bias[z];
    const float scale = P.scale[z];
    const int mode = P.mode[z];

    __shared__ short lds[(BM + BN) * BKK];   // 24 KB
    short* As = lds;
    short* Bs = lds + BM * BKK;

    const int tid = threadIdx.x;
    const int wave = tid >> 6, lane = tid & 63;
    const int fm = lane & 15, quad = lane >> 4;
    const int m0 = blockIdx.y * BM, n0 = blockIdx.x * BN;

    int arow[4], acol[4];
    #pragma unroll
    for (int t = 0; t < 4; ++t) {
        int s = (wave * 4 + t) * 64 + lane;
        int row = s >> 3;
        int u = (s & 7) ^ (row & 7);
        arow[t] = row; acol[t] = u * 8;
    }
    int brow[2], bcol[2];
    #pragma unroll
    for (int t = 0; t < 2; ++t) {
        int s = (wave * 2 + t) * 64 + lane;
        int row = s >> 3;
        int u = (s & 7) ^ (row & 7);
        brow[t] = row; bcol[t] = u * 8;
    }

    int aoff[2][2], boff[4][2];
    #pragma unroll
    for (int mt = 0; mt < 2; ++mt)
        #pragma unroll
        for (int kst = 0; kst < 2; ++kst) {
            int row = wave * 32 + mt * 16 + fm;
            int u = quad + 4 * kst;
            aoff[mt][kst] = row * 64 + ((u ^ (row & 7)) * 8);
        }
    #pragma unroll
    for (int nt = 0; nt < 4; ++nt)
        #pragma unroll
        for (int kst = 0; kst < 2; ++kst) {
            int row = nt * 16 + fm;
            int u = quad + 4 * kst;
            boff[nt][kst] = row * 64 + ((u ^ (row & 7)) * 8);
        }

    f32x4 acc[2][4];
    #pragma unroll
    for (int mt = 0; mt < 2; ++mt)
        #pragma unroll
        for (int nt = 0; nt < 4; ++nt) acc[mt][nt] = (f32x4){0.f, 0.f, 0.f, 0.f};

    for (int k0 = 0; k0 < K; k0 += BKK) {
        __syncthreads();
        #pragma unroll
        for (int t = 0; t < 4; ++t)
            gload_lds16(A + (size_t)(m0 + arow[t]) * K + k0 + acol[t],
                        As + (wave * 4 + t) * 512);
        #pragma unroll
        for (int t = 0; t < 2; ++t)
            gload_lds16(Bt + (size_t)(n0 + brow[t]) * K + k0 + bcol[t],
                        Bs + (wave * 2 + t) * 512);
        __syncthreads();
        #pragma unroll
        for (int kst = 0; kst < 2; ++kst) {
            bf16x8 af[2], bfr[4];
            af[0] = *(const bf16x8*)(As + aoff[0][kst]);
            af[1] = *(const bf16x8*)(As + aoff[1][kst]);
            #pragma unroll
            for (int nt = 0; nt < 4; ++nt)
                bfr[nt] = *(const bf16x8*)(Bs + boff[nt][kst]);
            #pragma unroll
            for (int mt = 0; mt < 2; ++mt)
                #pragma unroll
                for (int nt = 0; nt < 4; ++nt)
                    acc[mt][nt] = __builtin_amdgcn_mfma_f32_16x16x32_bf16(
                        af[mt], bfr[nt], acc[mt][nt], 0, 0, 0);
        }
    }

    if (mode == 2) {
        __syncthreads();
        short (*T)[BM + 8] = (short(*)[BM + 8])&lds[0];
        #pragma unroll
        for (int mt = 0; mt < 2; ++mt)
            #pragma unroll
            for (int nt = 0; nt < 4; ++nt) {
                int nn = nt * 16 + fm;
                float bv = bias[n0 + nn];
                #pragma unroll
                for (int r = 0; r < 4; ++r) {
                    int mm = wave * 32 + mt * 16 + quad * 4 + r;
                    T[nn][mm] = f2bf((acc[mt][nt][r] + bv) * scale);
                }
            }
        __syncthreads();
        int b = m0 >> 9;
        int ibase = m0 & (L - 1);
        int hblk = n0 >> 6;
        int n = tid >> 2, seg = (tid & 3) * 32;
        short* dst = (short*)P.out[z] + (((size_t)(b * H + hblk) * DH + n) * L) + ibase + seg;
        #pragma unroll
        for (int c = 0; c < 4; ++c)
            *(bf16x8*)(dst + c * 8) = *(const bf16x8*)(&T[n][seg + c * 8]);
    } else {
        #pragma unroll
        for (int mt = 0; mt < 2; ++mt)
            #pragma unroll
            for (int nt = 0; nt < 4; ++nt) {
                int n = n0 + nt * 16 + fm;
                float bv = bias[n];
                #pragma unroll
                for (int r = 0; r < 4; ++r) {
                    int m = m0 + wave * 32 + mt * 16 + quad * 4 + r;
                    float val = (acc[mt][nt][r] + bv) * scale;
                    if (mode == 0) {
                        ((float*)P.out[z])[(size_t)m * N + n] = val;
                    } else {
                        int b = m >> 9, i = m & (L - 1);
                        int h = n >> 6, d = n & (DH - 1);
                        ((short*)P.out[z])[(((size_t)(b * H + h) * L + i) * DH) + d] = f2bf(val);
                    }
                }
            }
    }
}

// ---------------- ast scores -> Sast bf16 [b][i][h][j] ----------------
// idx prefetch: all 8 mat indices loaded up front so emb gathers pipeline.
__global__ __launch_bounds__(256) void ast_kernel(
    const short* __restrict__ Qb, const int* __restrict__ mat,
    const short* __restrict__ semb, const short* __restrict__ vemb,
    short* __restrict__ Sast)
{
    const int i = blockIdx.x, b = blockIdx.y;
    const int tid = threadIdx.x;
    const int wave = tid >> 6, lane = tid & 63;
    const int fm = lane & 15, quad = lane >> 4;
    __shared__ short Sl[H][L + 8];

    const short* qp = Qb + (((size_t)(b * H + fm) * L + i) * DH);
    bf16x8 a0 = *(const bf16x8*)(qp + quad * 8);
    bf16x8 a1 = *(const bf16x8*)(qp + 32 + quad * 8);

    const int* mrow = mat + ((size_t)b * L + i) * L;

    int idxs[8];
    const short* ebase[8];
    #pragma unroll
    for (int t = 0; t < 8; ++t) {
        int j = (wave + t * 4) * 16 + fm;
        idxs[t] = mrow[j];
    }
    #pragma unroll
    for (int t = 0; t < 8; ++t) {
        int j = (wave + t * 4) * 16 + fm;
        ebase[t] = ((j & 1) ? vemb : semb) + (size_t)idxs[t] * DH;
    }

    #pragma unroll
    for (int t = 0; t < 8; ++t) {
        int j = (wave + t * 4) * 16 + fm;
        bf16x8 b0 = *(const bf16x8*)(ebase[t] + quad * 8);
        bf16x8 b1 = *(const bf16x8*)(ebase[t] + 32 + quad * 8);
        f32x4 c = {0.f, 0.f, 0.f, 0.f};
        c = __builtin_amdgcn_mfma_f32_16x16x32_bf16(a0, b0, c, 0, 0, 0);
        c = __builtin_amdgcn_mfma_f32_16x16x32_bf16(a1, b1, c, 0, 0, 0);
        #pragma unroll
        for (int r = 0; r < 4; ++r)
            Sl[quad * 4 + r][j] = f2bf(c[r]);
    }
    __syncthreads();
    int hh = tid >> 4, j0 = (tid & 15) * 32;
    short* dst = Sast + ((((size_t)b * L + i) * H + hh) * L) + j0;
    #pragma unroll
    for (int c = 0; c < 4; ++c)
        *(bf16x8*)(dst + c * 8) = *(const bf16x8*)(&Sl[hh][j0 + c * 8]);
}

// ---------------- fused qk + ast-add + softmax + PV, 32 i-rows per block ----------------
__global__ __launch_bounds__(256) void attn_fused_kernel(
    const short* __restrict__ Qb, const short* __restrict__ Kb,
    const short* __restrict__ Vt, const short* __restrict__ Sast,
    const unsigned char* __restrict__ mask,
    float* __restrict__ attn, short* __restrict__ ctx)
{
    const int i0 = blockIdx.x * 32;
    const int h = blockIdx.y;
    const int b = blockIdx.z;
    const int tid = threadIdx.x;
    const int wave = tid >> 6, lane = tid & 63;
    const int fm = lane & 15, quad = lane >> 4;

    __shared__ short Pb[32][L + 8];    // Sast staging, then P bf16 (33.3 KB)
    __shared__ float red_m[4][32];
    __shared__ float red_l[4][32];

    // stage Sast rows i0..i0+31, slice h (coalesced 16B loads)
    {
        int r = tid >> 3, seg = (tid & 7) * 64;
        const short* sp = Sast + ((((size_t)b * L + i0 + r) * H + h) * L) + seg;
        #pragma unroll
        for (int c = 0; c < 8; ++c)
            *(bf16x8*)(&Pb[r][seg + c * 8]) = *(const bf16x8*)(sp + c * 8);
    }

    // Q fragments for both row-tiles
    const short* qp0 = Qb + (((size_t)(b * H + h) * L + i0 + fm) * DH);
    const short* qp1 = qp0 + 16 * DH;
    bf16x8 a00 = *(const bf16x8*)(qp0 + quad * 8);
    bf16x8 a01 = *(const bf16x8*)(qp0 + 32 + quad * 8);
    bf16x8 a10 = *(const bf16x8*)(qp1 + quad * 8);
    bf16x8 a11 = *(const bf16x8*)(qp1 + 32 + quad * 8);
    const short* Kbase = Kb + ((size_t)(b * H + h) * L) * DH;
    __syncthreads();   // staging complete

    float s[8][2][4];
    float mx[2][4];
    #pragma unroll
    for (int rt = 0; rt < 2; ++rt)
        #pragma unroll
        for (int r = 0; r < 4; ++r) mx[rt][r] = -3.0e38f;

    #pragma unroll
    for (int t = 0; t < 8; ++t) {
        int j = (wave + t * 4) * 16 + fm;
        const short* kr = Kbase + (size_t)j * DH;
        bf16x8 b0 = *(const bf16x8*)(kr + quad * 8);
        bf16x8 b1 = *(const bf16x8*)(kr + 32 + quad * 8);
        f32x4 c0 = {0.f, 0.f, 0.f, 0.f};
        f32x4 c1 = {0.f, 0.f, 0.f, 0.f};
        c0 = __builtin_amdgcn_mfma_f32_16x16x32_bf16(a00, b0, c0, 0, 0, 0);
        c0 = __builtin_amdgcn_mfma_f32_16x16x32_bf16(a01, b1, c0, 0, 0, 0);
        c1 = __builtin_amdgcn_mfma_f32_16x16x32_bf16(a10, b0, c1, 0, 0, 0);
        c1 = __builtin_amdgcn_mfma_f32_16x16x32_bf16(a11, b1, c1, 0, 0, 0);
        bool mk = mask[(size_t)b * L + j] != 0;
        #pragma unroll
        for (int rt = 0; rt < 2; ++rt) {
            f32x4 c = rt ? c1 : c0;
            #pragma unroll
            for (int r = 0; r < 4; ++r) {
                int ir = rt * 16 + quad * 4 + r;
                float sv = c[r] + bf2f(Pb[ir][j]);
                sv = mk ? -1e18f : sv;
                s[t][rt][r] = sv;
                mx[rt][r] = fmaxf(mx[rt][r], sv);
            }
        }
    }

    // row max across fm lanes, then across waves
    #pragma unroll
    for (int off = 1; off <= 8; off <<= 1)
        #pragma unroll
        for (int rt = 0; rt < 2; ++rt)
            #pragma unroll
            for (int r = 0; r < 4; ++r)
                mx[rt][r] = fmaxf(mx[rt][r], __shfl_xor(mx[rt][r], off));
    if (fm == 0)
        #pragma unroll
        for (int rt = 0; rt < 2; ++rt)
            #pragma unroll
            for (int r = 0; r < 4; ++r)
                red_m[wave][rt * 16 + quad * 4 + r] = mx[rt][r];
    __syncthreads();
    float M_[2][4];
    #pragma unroll
    for (int rt = 0; rt < 2; ++rt)
        #pragma unroll
        for (int r = 0; r < 4; ++r) {
            int ir = rt * 16 + quad * 4 + r;
            M_[rt][r] = fmaxf(fmaxf(red_m[0][ir], red_m[1][ir]),
                              fmaxf(red_m[2][ir], red_m[3][ir]));
        }

    // exp + row sum
    float sum[2][4] = {{0.f, 0.f, 0.f, 0.f}, {0.f, 0.f, 0.f, 0.f}};
    #pragma unroll
    for (int t = 0; t < 8; ++t)
        #pragma unroll
        for (int rt = 0; rt < 2; ++rt)
            #pragma unroll
            for (int r = 0; r < 4; ++r) {
                float e = __expf(s[t][rt][r] - M_[rt][r]);
                s[t][rt][r] = e;
                sum[rt][r] += e;
            }
    #pragma unroll
    for (int off = 1; off <= 8; off <<= 1)
        #pragma unroll
        for (int rt = 0; rt < 2; ++rt)
            #pragma unroll
            for (int r = 0; r < 4; ++r)
                sum[rt][r] += __shfl_xor(sum[rt][r], off);
    if (fm == 0)
        #pragma unroll
        for (int rt = 0; rt < 2; ++rt)
            #pragma unroll
            for (int r = 0; r < 4; ++r)
                red_l[wave][rt * 16 + quad * 4 + r] = sum[rt][r];
    __syncthreads();
    float inv[2][4];
    #pragma unroll
    for (int rt = 0; rt < 2; ++rt)
        #pragma unroll
        for (int r = 0; r < 4; ++r) {
            int ir = rt * 16 + quad * 4 + r;
            inv[rt][r] = 1.f / (red_l[0][ir] + red_l[1][ir] + red_l[2][ir] + red_l[3][ir]);
        }

    // normalize: write attn fp32 + Pb bf16
    #pragma unroll
    for (int t = 0; t < 8; ++t) {
        int j = (wave + t * 4) * 16 + fm;
        #pragma unroll
        for (int rt = 0; rt < 2; ++rt)
            #pragma unroll
            for (int r = 0; r < 4; ++r) {
                int ir = rt * 16 + quad * 4 + r;
                float p = s[t][rt][r] * inv[rt][r];
                attn[(((size_t)(b * H + h) * L + i0 + ir) * L) + j] = p;
                Pb[ir][j] = f2bf(p);
            }
    }
    __syncthreads();

    // PV via MFMA: wave owns d-tile [wave*16, wave*16+16); 2 independent chains
    const short* Vb = Vt + (((size_t)(b * H + h) * DH + wave * 16 + fm) * L);
    f32x4 o0 = {0.f, 0.f, 0.f, 0.f};
    f32x4 o1 = {0.f, 0.f, 0.f, 0.f};
    for (int ks = 0; ks < L; ks += 32) {
        bf16x8 vb = *(const bf16x8*)(Vb + ks + quad * 8);
        bf16x8 p0 = *(const bf16x8*)(&Pb[fm][ks + quad * 8]);
        bf16x8 p1 = *(const bf16x8*)(&Pb[16 + fm][ks + quad * 8]);
        o0 = __builtin_amdgcn_mfma_f32_16x16x32_bf16(p0, vb, o0, 0, 0, 0);
        o1 = __builtin_amdgcn_mfma_f32_16x16x32_bf16(p1, vb, o1, 0, 0, 0);
    }
    #pragma unroll
    for (int r = 0; r < 4; ++r) {
        ctx[((size_t)b * L + i0 + quad * 4 + r) * D + h * DH + wave * 16 + fm] = f2bf(o0[r]);
        ctx[((size_t)b * L + i0 + 16 + quad * 4 + r) * D + h * DH + wave * 16 + fm] = f2bf(o1[r]);
    }
}

extern "C" void kernel_launch(void* const* d_in, const int* in_sizes, int n_in,
                              void* d_out, int out_size, void* d_ws, size_t ws_size,
                              hipStream_t stream) {
    const float* key_in   = (const float*)d_in[0];
    const float* value_in = (const float*)d_in[1];
    const float* query_in = (const float*)d_in[2];
    const int*   mat      = (const int*)d_in[3];
    const unsigned char* mask = (const unsigned char*)d_in[4];
    const float* Wq = (const float*)d_in[5];
    const float* bq = (const float*)d_in[6];
    const float* Wk = (const float*)d_in[7];
    const float* bk = (const float*)d_in[8];
    const float* Wv = (const float*)d_in[9];
    const float* bv = (const float*)d_in[10];
    const float* Wo = (const float*)d_in[11];
    const float* bo = (const float*)d_in[12];
    const float* struct_emb = (const float*)d_in[13];
    const float* value_emb  = (const float*)d_in[14];

    const int B = in_sizes[2] / (L * D);   // 4
    const int M = B * L;                   // 2048

    short* p = (short*)d_ws;
    short* xk  = p;  p += (size_t)M * D;
    short* xv  = p;  p += (size_t)M * D;
    short* xq  = p;  p += (size_t)M * D;
    short* WqT = p;  p += (size_t)D * D;
    short* WkT = p;  p += (size_t)D * D;
    short* WvT = p;  p += (size_t)D * D;
    short* WoT = p;  p += (size_t)D * D;
    short* semb = p; p += 16384;
    short* vemb = p; p += (size_t)in_sizes[14];
    short* Qb = p;   p += (size_t)M * D;
    short* Kb = p;   p += (size_t)M * D;
    short* Vt = p;   p += (size_t)M * D;
    short* Sast = p; p += (size_t)B * L * H * L;
    short* ctx = xk;   // dead after QKV projections; reused stream-ordered

    float* out_p  = (float*)d_out;
    float* attn_p = out_p + (size_t)M * D;

    PrepArgs pa;
    pa.csrc[0] = key_in;     pa.cdst[0] = xk;   pa.cn[0] = M * D;
    pa.csrc[1] = value_in;   pa.cdst[1] = xv;   pa.cn[1] = M * D;
    pa.csrc[2] = query_in;   pa.cdst[2] = xq;   pa.cn[2] = M * D;
    pa.csrc[3] = struct_emb; pa.cdst[3] = semb; pa.cn[3] = in_sizes[13];
    pa.csrc[4] = value_emb;  pa.cdst[4] = vemb; pa.cn[4] = in_sizes[14];
    pa.W[0] = Wq; pa.W[1] = Wk; pa.W[2] = Wv; pa.W[3] = Wo;
    pa.T[0] = WqT; pa.T[1] = WkT; pa.T[2] = WvT; pa.T[3] = WoT;
    prep_kernel<<<dim3((M * D) / 2048, 9), 256, 0, stream>>>(pa);

    GemmBatch qkv;
    qkv.A[0] = xq; qkv.Bt[0] = WqT; qkv.bias[0] = bq; qkv.out[0] = Qb; qkv.scale[0] = 0.125f; qkv.mode[0] = 1;
    qkv.A[1] = xk; qkv.Bt[1] = WkT; qkv.bias[1] = bk; qkv.out[1] = Kb; qkv.scale[1] = 1.0f;   qkv.mode[1] = 1;
    qkv.A[2] = xv; qkv.Bt[2] = WvT; qkv.bias[2] = bv; qkv.out[2] = Vt; qkv.scale[2] = 1.0f;   qkv.mode[2] = 2;
    gemm_mfma_kernel<<<dim3(D / BN, M / BM, 3), 256, 0, stream>>>(qkv, M, D, D);

    ast_kernel<<<dim3(L, B), 256, 0, stream>>>(Qb, mat, semb, vemb, Sast);

    attn_fused_kernel<<<dim3(L / 32, H, B), 256, 0, stream>>>(
        Qb, Kb, Vt, Sast, mask, attn_p, ctx);

    GemmBatch fin;
    fin.A[0] = ctx; fin.Bt[0] = WoT; fin.bias[0] = bo; fin.out[0] = out_p; fin.scale[0] = 1.0f; fin.mode[0] = 0;
    fin.A[1] = ctx; fin.Bt[1] = WoT; fin.bias[1] = bo; fin.out[1] = out_p; fin.scale[1] = 1.0f; fin.mode[1] = 0;
    fin.A[2] = ctx; fin.Bt[2] = WoT; fin.bias[2] = bo; fin.out[2] = out_p; fin.scale[2] = 1.0f; fin.mode[2] = 0;
    gemm_mfma_kernel<<<dim3(D / BN, M / BM, 1), 256, 0, stream>>>(fin, M, D, D);
}

// Round 6
// 241.387 us; speedup vs baseline: 1.0194x; 1.0194x over previous
//
#include <hip/hip_runtime.h>
#include <cstddef>

#define H 16
#define D 1024
#define DH 64
#define L 512

typedef __attribute__((ext_vector_type(8))) short bf16x8;
typedef __attribute__((ext_vector_type(4))) short bf16x4;
typedef __attribute__((ext_vector_type(4))) float f32x4;

__device__ inline short f2bf(float x) {
    union { float f; unsigned u; } c; c.f = x;
    unsigned r = (c.u + 0x7FFFu + ((c.u >> 16) & 1u)) >> 16;
    return (short)r;
}
__device__ inline float bf2f(short x) {
    union { float f; unsigned u; } c;
    c.u = ((unsigned)(unsigned short)x) << 16; return c.f;
}

__device__ inline void gload_lds16(const void* g, void* l) {
    __builtin_amdgcn_global_load_lds(
        (const __attribute__((address_space(1))) unsigned int*)g,
        (__attribute__((address_space(3))) unsigned int*)l,
        16, 0, 0);
}

// ---------------- prep: fp32->bf16 convert (5 regions) + 4 weight transposes ----------------
struct PrepArgs {
    const float* csrc[5]; short* cdst[5]; int cn[5];
    const float* W[4]; short* T[4];
};

__global__ __launch_bounds__(256) void prep_kernel(PrepArgs a) {
    const int y = blockIdx.y;
    if (y < 5) {
        const float* s = a.csrc[y];
        short* d = a.cdst[y];
        int n = a.cn[y];
        int i = (blockIdx.x * 256 + threadIdx.x) * 8;
        if (i >= n) return;
        float4 x0 = *(const float4*)(s + i);
        float4 x1 = *(const float4*)(s + i + 4);
        bf16x8 o;
        o[0] = f2bf(x0.x); o[1] = f2bf(x0.y); o[2] = f2bf(x0.z); o[3] = f2bf(x0.w);
        o[4] = f2bf(x1.x); o[5] = f2bf(x1.y); o[6] = f2bf(x1.z); o[7] = f2bf(x1.w);
        *(bf16x8*)(d + i) = o;
    } else {
        const float* W = a.W[y - 5];
        short* T = a.T[y - 5];
        int idx = blockIdx.x * 256 + threadIdx.x;
        if (idx >= 1024 * 128) return;
        int n = idx & 1023;
        int k0 = (idx >> 10) << 3;
        bf16x8 o;
        #pragma unroll
        for (int kk = 0; kk < 8; ++kk)
            o[kk] = f2bf(W[(size_t)(k0 + kk) * 1024 + n]);
        *(bf16x8*)(T + (size_t)n * 1024 + k0) = o;
    }
}

// ---------------- MFMA GEMM, m97-style: global_load_lds + XOR-swizzled LDS ----------------
#define BM 128
#define BN 64
#define BKK 64

struct GemmBatch {
    const short* A[3]; const short* Bt[3]; const float* bias[3];
    void* out[3]; float scale[3]; int mode[3];
};

__global__ __launch_bounds__(256) void gemm_mfma_kernel(GemmBatch P, int M, int N, int K) {
    const int z = blockIdx.z;
    const short* __restrict__ A  = P.A[z];
    const short* __restrict__ Bt = P.Bt[z];
    const float* __restrict__ bias = P.bias[z];
    const float scale = P.scale[z];
    const int mode = P.mode[z];

    __shared__ short lds[(BM + BN) * BKK];
    short* As = lds;
    short* Bs = lds + BM * BKK;

    const int tid = threadIdx.x;
    const int wave = tid >> 6, lane = tid & 63;
    const int fm = lane & 15, quad = lane >> 4;
    const int m0 = blockIdx.y * BM, n0 = blockIdx.x * BN;

    int arow[4], acol[4];
    #pragma unroll
    for (int t = 0; t < 4; ++t) {
        int s = (wave * 4 + t) * 64 + lane;
        int row = s >> 3;
        int u = (s & 7) ^ (row & 7);
        arow[t] = row; acol[t] = u * 8;
    }
    int brow[2], bcol[2];
    #pragma unroll
    for (int t = 0; t < 2; ++t) {
        int s = (wave * 2 + t) * 64 + lane;
        int row = s >> 3;
        int u = (s & 7) ^ (row & 7);
        brow[t] = row; bcol[t] = u * 8;
    }

    int aoff[2][2], boff[4][2];
    #pragma unroll
    for (int mt = 0; mt < 2; ++mt)
        #pragma unroll
        for (int kst = 0; kst < 2; ++kst) {
            int row = wave * 32 + mt * 16 + fm;
            int u = quad + 4 * kst;
            aoff[mt][kst] = row * 64 + ((u ^ (row & 7)) * 8);
        }
    #pragma unroll
    for (int nt = 0; nt < 4; ++nt)
        #pragma unroll
        for (int kst = 0; kst < 2; ++kst) {
            int row = nt * 16 + fm;
            int u = quad + 4 * kst;
            boff[nt][kst] = row * 64 + ((u ^ (row & 7)) * 8);
        }

    f32x4 acc[2][4];
    #pragma unroll
    for (int mt = 0; mt < 2; ++mt)
        #pragma unroll
        for (int nt = 0; nt < 4; ++nt) acc[mt][nt] = (f32x4){0.f, 0.f, 0.f, 0.f};

    for (int k0 = 0; k0 < K; k0 += BKK) {
        __syncthreads();
        #pragma unroll
        for (int t = 0; t < 4; ++t)
            gload_lds16(A + (size_t)(m0 + arow[t]) * K + k0 + acol[t],
                        As + (wave * 4 + t) * 512);
        #pragma unroll
        for (int t = 0; t < 2; ++t)
            gload_lds16(Bt + (size_t)(n0 + brow[t]) * K + k0 + bcol[t],
                        Bs + (wave * 2 + t) * 512);
        __syncthreads();
        #pragma unroll
        for (int kst = 0; kst < 2; ++kst) {
            bf16x8 af[2], bfr[4];
            af[0] = *(const bf16x8*)(As + aoff[0][kst]);
            af[1] = *(const bf16x8*)(As + aoff[1][kst]);
            #pragma unroll
            for (int nt = 0; nt < 4; ++nt)
                bfr[nt] = *(const bf16x8*)(Bs + boff[nt][kst]);
            #pragma unroll
            for (int mt = 0; mt < 2; ++mt)
                #pragma unroll
                for (int nt = 0; nt < 4; ++nt)
                    acc[mt][nt] = __builtin_amdgcn_mfma_f32_16x16x32_bf16(
                        af[mt], bfr[nt], acc[mt][nt], 0, 0, 0);
        }
    }

    if (mode == 2) {
        __syncthreads();
        short (*T)[BM + 8] = (short(*)[BM + 8])&lds[0];
        #pragma unroll
        for (int mt = 0; mt < 2; ++mt)
            #pragma unroll
            for (int nt = 0; nt < 4; ++nt) {
                int nn = nt * 16 + fm;
                float bv = bias[n0 + nn];
                #pragma unroll
                for (int r = 0; r < 4; ++r) {
                    int mm = wave * 32 + mt * 16 + quad * 4 + r;
                    T[nn][mm] = f2bf((acc[mt][nt][r] + bv) * scale);
                }
            }
        __syncthreads();
        int b = m0 >> 9;
        int ibase = m0 & (L - 1);
        int hblk = n0 >> 6;
        int n = tid >> 2, seg = (tid & 3) * 32;
        short* dst = (short*)P.out[z] + (((size_t)(b * H + hblk) * DH + n) * L) + ibase + seg;
        #pragma unroll
        for (int c = 0; c < 4; ++c)
            *(bf16x8*)(dst + c * 8) = *(const bf16x8*)(&T[n][seg + c * 8]);
    } else {
        #pragma unroll
        for (int mt = 0; mt < 2; ++mt)
            #pragma unroll
            for (int nt = 0; nt < 4; ++nt) {
                int n = n0 + nt * 16 + fm;
                float bv = bias[n];
                #pragma unroll
                for (int r = 0; r < 4; ++r) {
                    int m = m0 + wave * 32 + mt * 16 + quad * 4 + r;
                    float val = (acc[mt][nt][r] + bv) * scale;
                    if (mode == 0) {
                        ((float*)P.out[z])[(size_t)m * N + n] = val;
                    } else {
                        int b = m >> 9, i = m & (L - 1);
                        int h = n >> 6, d = n & (DH - 1);
                        ((short*)P.out[z])[(((size_t)(b * H + h) * L + i) * DH) + d] = f2bf(val);
                    }
                }
            }
    }
}

// ---------------- ast scores -> Sast bf16 [b][i][h][j] ----------------
__global__ __launch_bounds__(256) void ast_kernel(
    const short* __restrict__ Qb, const int* __restrict__ mat,
    const short* __restrict__ semb, const short* __restrict__ vemb,
    short* __restrict__ Sast)
{
    const int i = blockIdx.x, b = blockIdx.y;
    const int tid = threadIdx.x;
    const int wave = tid >> 6, lane = tid & 63;
    const int fm = lane & 15, quad = lane >> 4;
    __shared__ short Sl[H][L + 8];

    const short* qp = Qb + (((size_t)(b * H + fm) * L + i) * DH);
    bf16x8 a0 = *(const bf16x8*)(qp + quad * 8);
    bf16x8 a1 = *(const bf16x8*)(qp + 32 + quad * 8);

    const int* mrow = mat + ((size_t)b * L + i) * L;

    int idxs[8];
    const short* ebase[8];
    #pragma unroll
    for (int t = 0; t < 8; ++t) {
        int j = (wave + t * 4) * 16 + fm;
        idxs[t] = mrow[j];
    }
    #pragma unroll
    for (int t = 0; t < 8; ++t) {
        int j = (wave + t * 4) * 16 + fm;
        ebase[t] = ((j & 1) ? vemb : semb) + (size_t)idxs[t] * DH;
    }

    #pragma unroll
    for (int t = 0; t < 8; ++t) {
        int j = (wave + t * 4) * 16 + fm;
        bf16x8 b0 = *(const bf16x8*)(ebase[t] + quad * 8);
        bf16x8 b1 = *(const bf16x8*)(ebase[t] + 32 + quad * 8);
        f32x4 c = {0.f, 0.f, 0.f, 0.f};
        c = __builtin_amdgcn_mfma_f32_16x16x32_bf16(a0, b0, c, 0, 0, 0);
        c = __builtin_amdgcn_mfma_f32_16x16x32_bf16(a1, b1, c, 0, 0, 0);
        #pragma unroll
        for (int r = 0; r < 4; ++r)
            Sl[quad * 4 + r][j] = f2bf(c[r]);
    }
    __syncthreads();
    int hh = tid >> 4, j0 = (tid & 15) * 32;
    short* dst = Sast + ((((size_t)b * L + i) * H + hh) * L) + j0;
    #pragma unroll
    for (int c = 0; c < 4; ++c)
        *(bf16x8*)(dst + c * 8) = *(const bf16x8*)(&Sl[hh][j0 + c * 8]);
}

// ---------------- fused qk + ast-add + softmax + PV, 16 i-rows per block ----------------
// attn written from LDS bf16 P (coalesced float4); LDS stays ~17 KB -> high occupancy.
__global__ __launch_bounds__(256) void attn_fused_kernel(
    const short* __restrict__ Qb, const short* __restrict__ Kb,
    const short* __restrict__ Vt, const short* __restrict__ Sast,
    const unsigned char* __restrict__ mask,
    float* __restrict__ attn, short* __restrict__ ctx)
{
    const int i0 = blockIdx.x * 16;
    const int h = blockIdx.y;
    const int b = blockIdx.z;
    const int tid = threadIdx.x;
    const int wave = tid >> 6, lane = tid & 63;
    const int fm = lane & 15, quad = lane >> 4;

    __shared__ short Pb[16][L + 8];    // Sast staging -> P bf16 (16.6 KB)
    __shared__ float red_m[4][16];
    __shared__ float red_l[4][16];

    // stage Sast rows i0..i0+15, head h (coalesced b128)
    {
        int r = tid >> 4, seg = (tid & 15) * 32;
        const short* sp = Sast + ((((size_t)b * L + i0 + r) * H + h) * L) + seg;
        #pragma unroll
        for (int c = 0; c < 4; ++c)
            *(bf16x8*)(&Pb[r][seg + c * 8]) = *(const bf16x8*)(sp + c * 8);
    }

    // Q fragment: rows i0+fm
    const short* qp = Qb + (((size_t)(b * H + h) * L + i0 + fm) * DH);
    bf16x8 a0 = *(const bf16x8*)(qp + quad * 8);
    bf16x8 a1 = *(const bf16x8*)(qp + 32 + quad * 8);
    const short* Kbase = Kb + ((size_t)(b * H + h) * L) * DH;
    __syncthreads();

    // scores: wave owns j-range [wave*128, wave*128+128)
    float s[8][4];
    float mx[4] = {-3.0e38f, -3.0e38f, -3.0e38f, -3.0e38f};
    #pragma unroll
    for (int t = 0; t < 8; ++t) {
        int j = wave * 128 + t * 16 + fm;
        const short* kr = Kbase + (size_t)j * DH;
        bf16x8 b0 = *(const bf16x8*)(kr + quad * 8);
        bf16x8 b1 = *(const bf16x8*)(kr + 32 + quad * 8);
        f32x4 c = {0.f, 0.f, 0.f, 0.f};
        c = __builtin_amdgcn_mfma_f32_16x16x32_bf16(a0, b0, c, 0, 0, 0);
        c = __builtin_amdgcn_mfma_f32_16x16x32_bf16(a1, b1, c, 0, 0, 0);
        bool mk = mask[(size_t)b * L + j] != 0;
        #pragma unroll
        for (int r = 0; r < 4; ++r) {
            int ir = quad * 4 + r;
            float sv = c[r] + bf2f(Pb[ir][j]);
            sv = mk ? -1e18f : sv;
            s[t][r] = sv;
            mx[r] = fmaxf(mx[r], sv);
        }
    }

    // row max: shuffle over fm, then cross-wave via LDS
    #pragma unroll
    for (int off = 1; off <= 8; off <<= 1)
        #pragma unroll
        for (int r = 0; r < 4; ++r)
            mx[r] = fmaxf(mx[r], __shfl_xor(mx[r], off));
    if (fm == 0)
        #pragma unroll
        for (int r = 0; r < 4; ++r) red_m[wave][quad * 4 + r] = mx[r];
    __syncthreads();
    float M_[4];
    #pragma unroll
    for (int r = 0; r < 4; ++r) {
        int ir = quad * 4 + r;
        M_[r] = fmaxf(fmaxf(red_m[0][ir], red_m[1][ir]),
                      fmaxf(red_m[2][ir], red_m[3][ir]));
    }

    // exp + row sum
    float sum[4] = {0.f, 0.f, 0.f, 0.f};
    #pragma unroll
    for (int t = 0; t < 8; ++t)
        #pragma unroll
        for (int r = 0; r < 4; ++r) {
            float e = __expf(s[t][r] - M_[r]);
            s[t][r] = e;
            sum[r] += e;
        }
    #pragma unroll
    for (int off = 1; off <= 8; off <<= 1)
        #pragma unroll
        for (int r = 0; r < 4; ++r)
            sum[r] += __shfl_xor(sum[r], off);
    if (fm == 0)
        #pragma unroll
        for (int r = 0; r < 4; ++r) red_l[wave][quad * 4 + r] = sum[r];
    __syncthreads();
    float inv[4];
    #pragma unroll
    for (int r = 0; r < 4; ++r) {
        int ir = quad * 4 + r;
        inv[r] = 1.f / (red_l[0][ir] + red_l[1][ir] + red_l[2][ir] + red_l[3][ir]);
    }

    // normalize -> Pb bf16 (P buffer; attn written from here afterwards)
    #pragma unroll
    for (int t = 0; t < 8; ++t) {
        int j = wave * 128 + t * 16 + fm;
        #pragma unroll
        for (int r = 0; r < 4; ++r) {
            int ir = quad * 4 + r;
            Pb[ir][j] = f2bf(s[t][r] * inv[r]);
        }
    }
    __syncthreads();

    // attn write: coalesced float4 from Pb (bf16-rounded p; err <= ulp/2 ~ 9.8e-4)
    {
        int rowl = tid >> 4;            // 0..15
        int c0 = (tid & 15) * 8;        // lane-contiguous 32 B per lane
        float* arow = attn + (((size_t)(b * H + h) * L + i0 + rowl) * L);
        #pragma unroll
        for (int c = 0; c < 4; ++c) {
            int col = c0 + c * 128;
            bf16x8 pk = *(const bf16x8*)(&Pb[rowl][col]);
            float4 v0, v1;
            v0.x = bf2f(pk[0]); v0.y = bf2f(pk[1]); v0.z = bf2f(pk[2]); v0.w = bf2f(pk[3]);
            v1.x = bf2f(pk[4]); v1.y = bf2f(pk[5]); v1.z = bf2f(pk[6]); v1.w = bf2f(pk[7]);
            *(float4*)(arow + col) = v0;
            *(float4*)(arow + col + 4) = v1;
        }
    }

    // PV via MFMA: wave owns d-tile [wave*16, wave*16+16)
    const short* Vb = Vt + (((size_t)(b * H + h) * DH + wave * 16 + fm) * L);
    f32x4 o = {0.f, 0.f, 0.f, 0.f};
    for (int ks = 0; ks < L; ks += 32) {
        bf16x8 pa = *(const bf16x8*)(&Pb[fm][ks + quad * 8]);
        bf16x8 vb = *(const bf16x8*)(Vb + ks + quad * 8);
        o = __builtin_amdgcn_mfma_f32_16x16x32_bf16(pa, vb, o, 0, 0, 0);
    }
    #pragma unroll
    for (int r = 0; r < 4; ++r)
        ctx[((size_t)b * L + i0 + quad * 4 + r) * D + h * DH + wave * 16 + fm] = f2bf(o[r]);
}

extern "C" void kernel_launch(void* const* d_in, const int* in_sizes, int n_in,
                              void* d_out, int out_size, void* d_ws, size_t ws_size,
                              hipStream_t stream) {
    const float* key_in   = (const float*)d_in[0];
    const float* value_in = (const float*)d_in[1];
    const float* query_in = (const float*)d_in[2];
    const int*   mat      = (const int*)d_in[3];
    const unsigned char* mask = (const unsigned char*)d_in[4];
    const float* Wq = (const float*)d_in[5];
    const float* bq = (const float*)d_in[6];
    const float* Wk = (const float*)d_in[7];
    const float* bk = (const float*)d_in[8];
    const float* Wv = (const float*)d_in[9];
    const float* bv = (const float*)d_in[10];
    const float* Wo = (const float*)d_in[11];
    const float* bo = (const float*)d_in[12];
    const float* struct_emb = (const float*)d_in[13];
    const float* value_emb  = (const float*)d_in[14];

    const int B = in_sizes[2] / (L * D);   // 4
    const int M = B * L;                   // 2048

    short* p = (short*)d_ws;
    short* xk  = p;  p += (size_t)M * D;
    short* xv  = p;  p += (size_t)M * D;
    short* xq  = p;  p += (size_t)M * D;
    short* WqT = p;  p += (size_t)D * D;
    short* WkT = p;  p += (size_t)D * D;
    short* WvT = p;  p += (size_t)D * D;
    short* WoT = p;  p += (size_t)D * D;
    short* semb = p; p += 16384;
    short* vemb = p; p += (size_t)in_sizes[14];
    short* Qb = p;   p += (size_t)M * D;
    short* Kb = p;   p += (size_t)M * D;
    short* Vt = p;   p += (size_t)M * D;
    short* Sast = p; p += (size_t)B * L * H * L;
    short* ctx = xk;   // dead after QKV projections; reused stream-ordered

    float* out_p  = (float*)d_out;
    float* attn_p = out_p + (size_t)M * D;

    PrepArgs pa;
    pa.csrc[0] = key_in;     pa.cdst[0] = xk;   pa.cn[0] = M * D;
    pa.csrc[1] = value_in;   pa.cdst[1] = xv;   pa.cn[1] = M * D;
    pa.csrc[2] = query_in;   pa.cdst[2] = xq;   pa.cn[2] = M * D;
    pa.csrc[3] = struct_emb; pa.cdst[3] = semb; pa.cn[3] = in_sizes[13];
    pa.csrc[4] = value_emb;  pa.cdst[4] = vemb; pa.cn[4] = in_sizes[14];
    pa.W[0] = Wq; pa.W[1] = Wk; pa.W[2] = Wv; pa.W[3] = Wo;
    pa.T[0] = WqT; pa.T[1] = WkT; pa.T[2] = WvT; pa.T[3] = WoT;
    prep_kernel<<<dim3((M * D) / 2048, 9), 256, 0, stream>>>(pa);

    GemmBatch qkv;
    qkv.A[0] = xq; qkv.Bt[0] = WqT; qkv.bias[0] = bq; qkv.out[0] = Qb; qkv.scale[0] = 0.125f; qkv.mode[0] = 1;
    qkv.A[1] = xk; qkv.Bt[1] = WkT; qkv.bias[1] = bk; qkv.out[1] = Kb; qkv.scale[1] = 1.0f;   qkv.mode[1] = 1;
    qkv.A[2] = xv; qkv.Bt[2] = WvT; qkv.bias[2] = bv; qkv.out[2] = Vt; qkv.scale[2] = 1.0f;   qkv.mode[2] = 2;
    gemm_mfma_kernel<<<dim3(D / BN, M / BM, 3), 256, 0, stream>>>(qkv, M, D, D);

    ast_kernel<<<dim3(L, B), 256, 0, stream>>>(Qb, mat, semb, vemb, Sast);

    attn_fused_kernel<<<dim3(L / 16, H, B), 256, 0, stream>>>(
        Qb, Kb, Vt, Sast, mask, attn_p, ctx);

    GemmBatch fin;
    fin.A[0] = ctx; fin.Bt[0] = WoT; fin.bias[0] = bo; fin.out[0] = out_p; fin.scale[0] = 1.0f; fin.mode[0] = 0;
    fin.A[1] = ctx; fin.Bt[1] = WoT; fin.bias[1] = bo; fin.out[1] = out_p; fin.scale[1] = 1.0f; fin.mode[1] = 0;
    fin.A[2] = ctx; fin.Bt[2] = WoT; fin.bias[2] = bo; fin.out[2] = out_p; fin.scale[2] = 1.0f; fin.mode[2] = 0;
    gemm_mfma_kernel<<<dim3(D / BN, M / BM, 1), 256, 0, stream>>>(fin, M, D, D);
}